// Round 1
// baseline (496.596 us; speedup 1.0000x reference)
//
#include <hip/hip_runtime.h>

#define BB 16
#define NN 4096

// Pack database points as (x, y, x^2+y^2, 0) so the O(N^2) loop needs no
// per-target t2 recompute. packed[0..B*N) = pred, [B*N..2B*N) = target.
__global__ __launch_bounds__(256) void pack_db(
    const float* __restrict__ pred, const float* __restrict__ target,
    float4* __restrict__ packed) {
  int i = blockIdx.x * 256 + threadIdx.x;  // 0 .. 2*BB*NN
  const float* src = (i < BB * NN) ? pred : target;
  int j = (i < BB * NN) ? i : i - BB * NN;
  float x = src[2 * j];
  float y = src[2 * j + 1];
  packed[i] = make_float4(x, y, __builtin_fmaf(x, x, y * y), 0.0f);
}

// One thread = one query point. dir 0: query=pred, db=target (pred_to_target).
// dir 1: query=target, db=pred. Track m = t2 - 2*px*tx - 2*py*ty (argmin of
// d2 = m + p2 is argmin of m since p2 is constant per query).
// db[j] has a wave-uniform address -> scalar loads (s_load_dwordx4), keeping
// VALU as the only hot pipe.
__global__ __launch_bounds__(256) void chamfer_main(
    const float* __restrict__ pred, const float* __restrict__ target,
    const float4* __restrict__ packed, float* __restrict__ out) {
  const int id = blockIdx.x;          // 512 blocks
  const int dir = id & 1;
  const int b = (id >> 1) & 15;
  const int chunk = id >> 5;          // 0..15
  const float2* qsrc = (const float2*)(dir ? target : pred);
  const float4* __restrict__ db = packed + (dir ? 0 : BB * NN) + b * NN;

  const int q = chunk * 256 + threadIdx.x;
  const float2 Q = qsrc[b * NN + q];
  const float nx = -2.0f * Q.x;
  const float ny = -2.0f * Q.y;
  const float p2 = __builtin_fmaf(Q.x, Q.x, Q.y * Q.y);

  float m = 3.4e38f;
#pragma unroll 8
  for (int j = 0; j < NN; ++j) {
    const float4 t = db[j];
    m = fminf(m, __builtin_fmaf(nx, t.x, __builtin_fmaf(ny, t.y, t.z)));
  }
  float v = m + p2;  // min squared distance for this query point

  // Block-level sum reduction: wave shuffle tree, then LDS across 4 waves.
#pragma unroll
  for (int off = 32; off > 0; off >>= 1) v += __shfl_down(v, off, 64);
  __shared__ float red[4];
  if ((threadIdx.x & 63) == 0) red[threadIdx.x >> 6] = v;
  __syncthreads();
  if (threadIdx.x == 0) {
    const float s = (red[0] + red[1]) + (red[2] + red[3]);
    atomicAdd(&out[dir], s * (1.0f / 65536.0f));
  }
}

extern "C" void kernel_launch(void* const* d_in, const int* in_sizes, int n_in,
                              void* d_out, int out_size, void* d_ws, size_t ws_size,
                              hipStream_t stream) {
  const float* pred = (const float*)d_in[0];
  const float* target = (const float*)d_in[1];
  float* out = (float*)d_out;
  float4* packed = (float4*)d_ws;  // 2*16*4096*16 B = 2 MiB

  hipMemsetAsync(d_out, 0, 2 * sizeof(float), stream);
  pack_db<<<(2 * BB * NN) / 256, 256, 0, stream>>>(pred, target, packed);
  chamfer_main<<<512, 256, 0, stream>>>(pred, target, packed, out);
}

// Round 2
// 114.771 us; speedup vs baseline: 4.3269x; 4.3269x over previous
//
#include <hip/hip_runtime.h>

#define BB 16
#define NN 4096
#define HQ (BB * NN)        // 65536 queries per direction
#define QT (2 * HQ)         // 131072 total
#define NSLICE 8
#define SLICE_PTS (NN / NSLICE)  // 512

// Pack database points as (x, y, x^2+y^2, 0).
// packed[0..HQ) = pred points, [HQ..QT) = target points.
__global__ __launch_bounds__(256) void pack_db(
    const float* __restrict__ pred, const float* __restrict__ target,
    float4* __restrict__ packed) {
  int i = blockIdx.x * 256 + threadIdx.x;
  const float* src = (i < HQ) ? pred : target;
  int j = (i < HQ) ? i : i - HQ;
  float x = src[2 * j];
  float y = src[2 * j + 1];
  packed[i] = make_float4(x, y, __builtin_fmaf(x, x, y * y), 0.0f);
}

// P=4 queries per lane, db split into NSLICE slices.
// Block id bits: [0:2]=slice, [3:4]=qchunk, [5:8]=batch, [9]=dir.
// Tracks m = t2 - 2*qx*tx - 2*qy*ty; min d2 = m_min + q2 (added in reduce).
__global__ __launch_bounds__(256, 4) void chamfer_partial(
    const float* __restrict__ pred, const float* __restrict__ target,
    const float4* __restrict__ packed, float* __restrict__ partial) {
  const int id = blockIdx.x;
  const int slice = id & (NSLICE - 1);
  const int qc = (id >> 3) & 3;
  const int b = (id >> 5) & 15;
  const int dir = id >> 9;
  const int t = threadIdx.x;

  const float2* __restrict__ qsrc = (const float2*)(dir ? target : pred);
  const float4* __restrict__ db =
      packed + (dir ? 0 : HQ) + b * NN + slice * SLICE_PTS;

  const int qoff = b * NN + qc * 1024 + t;
  const float2 Q0 = qsrc[qoff];
  const float2 Q1 = qsrc[qoff + 256];
  const float2 Q2 = qsrc[qoff + 512];
  const float2 Q3 = qsrc[qoff + 768];
  const float nx0 = -2.0f * Q0.x, ny0 = -2.0f * Q0.y;
  const float nx1 = -2.0f * Q1.x, ny1 = -2.0f * Q1.y;
  const float nx2 = -2.0f * Q2.x, ny2 = -2.0f * Q2.y;
  const float nx3 = -2.0f * Q3.x, ny3 = -2.0f * Q3.y;

  float m0 = 3.4e38f, m1 = 3.4e38f, m2 = 3.4e38f, m3 = 3.4e38f;
#pragma unroll 8
  for (int j = 0; j < SLICE_PTS; ++j) {
    const float4 tp = db[j];
    m0 = fminf(m0, __builtin_fmaf(nx0, tp.x, __builtin_fmaf(ny0, tp.y, tp.z)));
    m1 = fminf(m1, __builtin_fmaf(nx1, tp.x, __builtin_fmaf(ny1, tp.y, tp.z)));
    m2 = fminf(m2, __builtin_fmaf(nx2, tp.x, __builtin_fmaf(ny2, tp.y, tp.z)));
    m3 = fminf(m3, __builtin_fmaf(nx3, tp.x, __builtin_fmaf(ny3, tp.y, tp.z)));
  }

  const int pbase = slice * QT + dir * HQ + b * NN + qc * 1024 + t;
  partial[pbase] = m0;
  partial[pbase + 256] = m1;
  partial[pbase + 512] = m2;
  partial[pbase + 768] = m3;
}

// Min-combine slices, add q^2, sum-reduce per block, atomicAdd per dir.
__global__ __launch_bounds__(256) void chamfer_reduce(
    const float4* __restrict__ packed, const float* __restrict__ partial,
    float* __restrict__ out) {
  const int idx = blockIdx.x * 256 + threadIdx.x;  // 0..QT
  float m = partial[idx];
#pragma unroll
  for (int s = 1; s < NSLICE; ++s) m = fminf(m, partial[s * QT + idx]);
  float v = m + packed[idx].z;  // packed index == global query index

#pragma unroll
  for (int off = 32; off > 0; off >>= 1) v += __shfl_down(v, off, 64);
  __shared__ float red[4];
  if ((threadIdx.x & 63) == 0) red[threadIdx.x >> 6] = v;
  __syncthreads();
  if (threadIdx.x == 0) {
    const int dir = blockIdx.x >> 8;  // 256 blocks per direction
    const float s = (red[0] + red[1]) + (red[2] + red[3]);
    atomicAdd(&out[dir], s * (1.0f / 65536.0f));
  }
}

extern "C" void kernel_launch(void* const* d_in, const int* in_sizes, int n_in,
                              void* d_out, int out_size, void* d_ws, size_t ws_size,
                              hipStream_t stream) {
  const float* pred = (const float*)d_in[0];
  const float* target = (const float*)d_in[1];
  float* out = (float*)d_out;
  float4* packed = (float4*)d_ws;                       // 2 MiB
  float* partial = (float*)((char*)d_ws + QT * 16);     // 4 MiB

  hipMemsetAsync(d_out, 0, 2 * sizeof(float), stream);
  pack_db<<<QT / 256, 256, 0, stream>>>(pred, target, packed);
  chamfer_partial<<<2 * 16 * 4 * NSLICE, 256, 0, stream>>>(pred, target, packed,
                                                           partial);
  chamfer_reduce<<<QT / 256, 256, 0, stream>>>(packed, partial, out);
}

// Round 3
// 91.984 us; speedup vs baseline: 5.3987x; 1.2477x over previous
//
#include <hip/hip_runtime.h>

#define BB 16
#define NN 4096
#define HQ (BB * NN)        // 65536 queries per direction
#define QT (2 * HQ)         // 131072 total
#define NSLICE 8
#define SLICE_PTS (NN / NSLICE)  // 512
#define PQ 4                     // queries per lane
#define QCHUNK (256 * PQ)        // 1024 queries per block
#define NQC (NN / QCHUNK)        // 4

typedef float v2f __attribute__((ext_vector_type(2)));

// Fused pack+partial. Block id bits: slice[0:2], qc[3:4], b[5:8], dir[9].
// Stages its 512-pt db slice into LDS as SoA (TX/TY/T2), then inner loop:
// per 4 db points per query = 4 v_pk_fma_f32 + 2 v_min3_f32.
// m = t2 - 2qx*tx - 2qy*ty tracked; q2 added in reduce.
__global__ __launch_bounds__(256, 4) void chamfer_partial(
    const float* __restrict__ pred, const float* __restrict__ target,
    float* __restrict__ partial) {
  const int id = blockIdx.x;  // 1024 blocks
  const int slice = id & (NSLICE - 1);
  const int qc = (id >> 3) & (NQC - 1);
  const int b = (id >> 5) & (BB - 1);
  const int dir = id >> 9;
  const int t = threadIdx.x;

  __shared__ __align__(16) float sTX[SLICE_PTS];
  __shared__ __align__(16) float sTY[SLICE_PTS];
  __shared__ __align__(16) float sT2[SLICE_PTS];

  // db = opposite cloud of query. Each thread packs 2 points.
  const float2* __restrict__ dsrc = (const float2*)(dir ? pred : target);
#pragma unroll
  for (int k = 0; k < SLICE_PTS / 256; ++k) {
    const int j = k * 256 + t;
    const float2 p = dsrc[b * NN + slice * SLICE_PTS + j];
    sTX[j] = p.x;
    sTY[j] = p.y;
    sT2[j] = __builtin_fmaf(p.x, p.x, p.y * p.y);
  }

  const float2* __restrict__ qsrc = (const float2*)(dir ? target : pred);
  const int qbase = b * NN + qc * QCHUNK + t;
  v2f nx[PQ], ny[PQ];
  float acc[PQ];
#pragma unroll
  for (int p = 0; p < PQ; ++p) {
    const float2 Q = qsrc[qbase + p * 256];
    const float fx = -2.0f * Q.x, fy = -2.0f * Q.y;
    nx[p] = {fx, fx};
    ny[p] = {fy, fy};
    acc[p] = 3.4e38f;
  }
  __syncthreads();

  const float4* __restrict__ qTX = (const float4*)sTX;
  const float4* __restrict__ qTY = (const float4*)sTY;
  const float4* __restrict__ qT2 = (const float4*)sT2;
#pragma unroll 2
  for (int g = 0; g < SLICE_PTS / 4; ++g) {
    const float4 x4 = qTX[g], y4 = qTY[g], s4 = qT2[g];
    const v2f xlo = {x4.x, x4.y}, xhi = {x4.z, x4.w};
    const v2f ylo = {y4.x, y4.y}, yhi = {y4.z, y4.w};
    const v2f slo = {s4.x, s4.y}, shi = {s4.z, s4.w};
#pragma unroll
    for (int p = 0; p < PQ; ++p) {
      v2f r0 = __builtin_elementwise_fma(ny[p], ylo, slo);
      r0 = __builtin_elementwise_fma(nx[p], xlo, r0);
      acc[p] = fminf(acc[p], fminf(r0.x, r0.y));  // v_min3_f32
      v2f r1 = __builtin_elementwise_fma(ny[p], yhi, shi);
      r1 = __builtin_elementwise_fma(nx[p], xhi, r1);
      acc[p] = fminf(acc[p], fminf(r1.x, r1.y));
    }
  }

  const int pbase = slice * QT + dir * HQ + b * NN + qc * QCHUNK + t;
#pragma unroll
  for (int p = 0; p < PQ; ++p) partial[pbase + p * 256] = acc[p];
}

// Min over slices (float4-vectorized), recompute q2 from raw inputs, add,
// block-sum, one atomicAdd per block. 128 blocks; dir uniform per block.
__global__ __launch_bounds__(256) void chamfer_reduce(
    const float* __restrict__ pred, const float* __restrict__ target,
    const float4* __restrict__ partial4, float* __restrict__ out) {
  const int i = blockIdx.x * 256 + threadIdx.x;  // 0 .. QT/4
  float4 m = partial4[i];
#pragma unroll
  for (int s = 1; s < NSLICE; ++s) {
    const float4 w = partial4[s * (QT / 4) + i];
    m.x = fminf(m.x, w.x);
    m.y = fminf(m.y, w.y);
    m.z = fminf(m.z, w.z);
    m.w = fminf(m.w, w.w);
  }
  const int dir = i >= (HQ / 4);
  const int q0 = i * 4 - dir * HQ;
  const float2* __restrict__ qsrc = (const float2*)(dir ? target : pred);
  const float2 Q0 = qsrc[q0], Q1 = qsrc[q0 + 1];
  const float2 Q2 = qsrc[q0 + 2], Q3 = qsrc[q0 + 3];
  float v = (m.x + __builtin_fmaf(Q0.x, Q0.x, Q0.y * Q0.y)) +
            (m.y + __builtin_fmaf(Q1.x, Q1.x, Q1.y * Q1.y)) +
            (m.z + __builtin_fmaf(Q2.x, Q2.x, Q2.y * Q2.y)) +
            (m.w + __builtin_fmaf(Q3.x, Q3.x, Q3.y * Q3.y));

#pragma unroll
  for (int off = 32; off > 0; off >>= 1) v += __shfl_down(v, off, 64);
  __shared__ float red[4];
  if ((threadIdx.x & 63) == 0) red[threadIdx.x >> 6] = v;
  __syncthreads();
  if (threadIdx.x == 0) {
    const float s = (red[0] + red[1]) + (red[2] + red[3]);
    atomicAdd(&out[dir], s * (1.0f / 65536.0f));
  }
}

extern "C" void kernel_launch(void* const* d_in, const int* in_sizes, int n_in,
                              void* d_out, int out_size, void* d_ws, size_t ws_size,
                              hipStream_t stream) {
  const float* pred = (const float*)d_in[0];
  const float* target = (const float*)d_in[1];
  float* out = (float*)d_out;
  float* partial = (float*)d_ws;  // NSLICE * QT * 4B = 4 MiB

  hipMemsetAsync(d_out, 0, 2 * sizeof(float), stream);
  chamfer_partial<<<2 * BB * NQC * NSLICE, 256, 0, stream>>>(pred, target,
                                                             partial);
  chamfer_reduce<<<QT / 4 / 256, 256, 0, stream>>>(pred, target,
                                                   (const float4*)partial, out);
}

// Round 4
// 89.144 us; speedup vs baseline: 5.5707x; 1.0319x over previous
//
#include <hip/hip_runtime.h>

#define BB 16
#define NN 4096
#define HQ (BB * NN)        // 65536 queries per direction
#define QT (2 * HQ)         // 131072 total
#define NSLICE 8
#define DBS (NN / NSLICE)   // 512 db points per block
#define WPTS (DBS / 4)      // 128 db points per wave
#define NGRP (WPTS / 4)     // 32 groups of 4 points
#define PQ 16               // queries per lane
#define QW (64 * PQ)        // 1024 queries per block (shared by all 4 waves)
#define NQC (NN / QW)       // 4 query chunks per batch

typedef float v2f __attribute__((ext_vector_type(2)));

// Block id bits: slice[0:2], qc[3:4], b[5:8], dir[9]. 1024 blocks.
// All 4 waves share one 1024-query set (PQ=16/lane); each wave owns a
// 128-pt quarter of the block's 512-pt db slice. Per group-of-4 points:
// 3 broadcast ds_read_b128 (36 LDS-cyc, CU-shared) vs 96 pk inst
// (192 SIMD-cyc) -> LDS demand 0.75: VALU-bound (round-3's PQ=4 was 3x
// LDS-oversubscribed). Cross-wave min-combine via LDS transpose.
__global__ __launch_bounds__(256, 4) void chamfer_partial(
    const float* __restrict__ pred, const float* __restrict__ target,
    float* __restrict__ partial) {
  const int bid = blockIdx.x;
  const int slice = bid & (NSLICE - 1);
  const int qc = (bid >> 3) & (NQC - 1);
  const int b = (bid >> 5) & (BB - 1);
  const int dir = bid >> 9;
  const int t = threadIdx.x;
  const int lane = t & 63;
  const int wid = t >> 6;

  // 16 KB: staging uses first 6 KB (3x512 floats); combine reuses all 16 KB.
  __shared__ float smem[4096];
  float* sTX = smem;
  float* sTY = smem + DBS;
  float* sT2 = smem + 2 * DBS;

  // Stage 512 db points (opposite cloud), 2 per thread, SoA + |t|^2.
  const float2* __restrict__ dsrc = (const float2*)(dir ? pred : target);
  {
    const float4 two = ((const float4*)(dsrc + b * NN + slice * DBS))[t];
    ((float2*)sTX)[t] = {two.x, two.z};
    ((float2*)sTY)[t] = {two.y, two.w};
    ((float2*)sT2)[t] = {__builtin_fmaf(two.x, two.x, two.y * two.y),
                         __builtin_fmaf(two.z, two.z, two.w * two.w)};
  }

  // Load this lane's 16 queries (same set for all 4 waves; L1-hot).
  const float2* __restrict__ qsrc = (const float2*)(dir ? target : pred);
  const int qbase = b * NN + qc * QW + lane;
  v2f nx[PQ], ny[PQ], acc[PQ];
#pragma unroll
  for (int k = 0; k < PQ; ++k) {
    const float2 Q = qsrc[qbase + k * 64];
    const float fx = -2.0f * Q.x, fy = -2.0f * Q.y;
    nx[k] = {fx, fx};
    ny[k] = {fy, fy};
    acc[k] = {3.4e38f, 3.4e38f};
  }
  __syncthreads();

  const float4* __restrict__ gx = (const float4*)sTX + wid * (WPTS / 4);
  const float4* __restrict__ gy = (const float4*)sTY + wid * (WPTS / 4);
  const float4* __restrict__ gs = (const float4*)sT2 + wid * (WPTS / 4);
  for (int g = 0; g < NGRP; ++g) {
    const float4 x4 = gx[g], y4 = gy[g], s4 = gs[g];
    const v2f xlo = {x4.x, x4.y}, xhi = {x4.z, x4.w};
    const v2f ylo = {y4.x, y4.y}, yhi = {y4.z, y4.w};
    const v2f slo = {s4.x, s4.y}, shi = {s4.z, s4.w};
#pragma unroll
    for (int k = 0; k < PQ; ++k) {
      v2f r0 = __builtin_elementwise_fma(ny[k], ylo, slo);
      r0 = __builtin_elementwise_fma(nx[k], xlo, r0);
      acc[k] = __builtin_elementwise_min(acc[k], r0);
      v2f r1 = __builtin_elementwise_fma(ny[k], yhi, shi);
      r1 = __builtin_elementwise_fma(nx[k], xhi, r1);
      acc[k] = __builtin_elementwise_min(acc[k], r1);
    }
  }

  __syncthreads();  // all waves done reading db before smem reuse
  // Per-lane mins -> cmb[k][wid][lane] (lane-contiguous: conflict-free).
#pragma unroll
  for (int k = 0; k < PQ; ++k)
    smem[(k * 4 + wid) * 64 + lane] = fminf(acc[k].x, acc[k].y);
  __syncthreads();

  // Thread t combines the 4 wave-mins for queries k = wid*4 .. wid*4+3.
  const int pbase = slice * QT + dir * HQ + b * NN + qc * QW + lane;
#pragma unroll
  for (int j = 0; j < 4; ++j) {
    const int k = wid * 4 + j;
    const float m = fminf(fminf(smem[(k * 4 + 0) * 64 + lane],
                                smem[(k * 4 + 1) * 64 + lane]),
                          fminf(smem[(k * 4 + 2) * 64 + lane],
                                smem[(k * 4 + 3) * 64 + lane]));
    partial[pbase + k * 64] = m;
  }
}

// Min over 8 slices (float4-vectorized), add |q|^2, block-sum -> bsum.
__global__ __launch_bounds__(256) void chamfer_reduce(
    const float* __restrict__ pred, const float* __restrict__ target,
    const float4* __restrict__ partial4, float* __restrict__ bsum) {
  const int i = blockIdx.x * 256 + threadIdx.x;  // 0 .. QT/4, 128 blocks
  float4 m = partial4[i];
#pragma unroll
  for (int s = 1; s < NSLICE; ++s) {
    const float4 w = partial4[s * (QT / 4) + i];
    m.x = fminf(m.x, w.x);
    m.y = fminf(m.y, w.y);
    m.z = fminf(m.z, w.z);
    m.w = fminf(m.w, w.w);
  }
  const int dir = i >= (HQ / 4);  // uniform per block
  const int q0 = i * 4 - dir * HQ;
  const float2* __restrict__ qsrc = (const float2*)(dir ? target : pred);
  const float2 Q0 = qsrc[q0], Q1 = qsrc[q0 + 1];
  const float2 Q2 = qsrc[q0 + 2], Q3 = qsrc[q0 + 3];
  float v = (m.x + __builtin_fmaf(Q0.x, Q0.x, Q0.y * Q0.y)) +
            (m.y + __builtin_fmaf(Q1.x, Q1.x, Q1.y * Q1.y)) +
            (m.z + __builtin_fmaf(Q2.x, Q2.x, Q2.y * Q2.y)) +
            (m.w + __builtin_fmaf(Q3.x, Q3.x, Q3.y * Q3.y));

#pragma unroll
  for (int off = 32; off > 0; off >>= 1) v += __shfl_down(v, off, 64);
  __shared__ float red[4];
  if ((threadIdx.x & 63) == 0) red[threadIdx.x >> 6] = v;
  __syncthreads();
  if (threadIdx.x == 0)
    bsum[blockIdx.x] = (red[0] + red[1]) + (red[2] + red[3]);
}

// 128 block-sums: blocks 0..63 are dir0, 64..127 dir1. One 2-wave block.
__global__ __launch_bounds__(128) void chamfer_final(
    const float* __restrict__ bsum, float* __restrict__ out) {
  const int t = threadIdx.x;
  float v = bsum[t];
#pragma unroll
  for (int off = 32; off > 0; off >>= 1) v += __shfl_down(v, off, 64);
  if ((t & 63) == 0) out[t >> 6] = v * (1.0f / 65536.0f);
}

extern "C" void kernel_launch(void* const* d_in, const int* in_sizes, int n_in,
                              void* d_out, int out_size, void* d_ws, size_t ws_size,
                              hipStream_t stream) {
  const float* pred = (const float*)d_in[0];
  const float* target = (const float*)d_in[1];
  float* out = (float*)d_out;
  float* partial = (float*)d_ws;                          // 4 MiB
  float* bsum = (float*)((char*)d_ws + NSLICE * QT * 4);  // 512 B

  chamfer_partial<<<2 * BB * NQC * NSLICE, 256, 0, stream>>>(pred, target,
                                                             partial);
  chamfer_reduce<<<QT / 4 / 256, 256, 0, stream>>>(pred, target,
                                                   (const float4*)partial, bsum);
  chamfer_final<<<1, 128, 0, stream>>>(bsum, out);
}